// Round 2
// baseline (737.045 us; speedup 1.0000x reference)
//
#include <hip/hip_runtime.h>

#define BATCH 16
#define SEQ   4096
#define HEADS 16
#define EMB   64
#define SS    64      // s = sqrt(SEQ)
#define NW    127     // 2*s - 1
#define HE    (HEADS*EMB)
#define EC    32      // e-chunk per block (EMB/2)

// Grid: BATCH*HEADS*2 = 512 blocks (2 blocks/CU). Block = (b, h, e-half).
// 512 threads: e4 = tid&7 (8 float4 slices covering 32 e's), irow = tid>>3 (0..63).
// Each thread owns row i=irow: u_s[i] accumulates in registers (no reduction);
// v_s[j] merges across the 64 row-threads via LDS atomicAdd (ds_add_f32).
__global__ __launch_bounds__(512) void pbv_kernel(const float* __restrict__ v,
                                                  const float* __restrict__ w,
                                                  float* __restrict__ out) {
    __shared__ float vs_l[SS][EC];   // v_s[j][e], later RxV
    __shared__ float us_l[SS][EC];   // u_s[i][e], later RxU
    __shared__ float wtab[NW];

    const int blk   = blockIdx.x;
    const int bh    = blk >> 1;
    const int half  = blk & 1;
    const int b     = bh / HEADS;
    const int h     = bh % HEADS;
    const int tid   = threadIdx.x;
    const int e4    = tid & 7;       // float4 slice within the 32-e chunk
    const int irow  = tid >> 3;      // 0..63 — owned i row (and t index in conv)
    const int ebase = half * EC;

    for (int idx = tid; idx < SS * EC; idx += 512) (&vs_l[0][0])[idx] = 0.0f;
    if (tid < NW) wtab[tid] = w[h * NW + tid];
    __syncthreads();

    // ---- phase 1: stream row irow, dwordx4 loads ----
    const float* rowbase = v + (((size_t)b * SEQ + (size_t)irow * SS) * HEADS + h) * EMB
                             + ebase + e4 * 4;
    float ua = 0.f, ub = 0.f, uc = 0.f, ud = 0.f;
    #pragma unroll 8
    for (int j = 0; j < SS; ++j) {
        const float4 val = *(const float4*)(rowbase + (size_t)j * HE);
        ua += val.x; ub += val.y; uc += val.z; ud += val.w;
        atomicAdd(&vs_l[j][e4 * 4 + 0], val.x);
        atomicAdd(&vs_l[j][e4 * 4 + 1], val.y);
        atomicAdd(&vs_l[j][e4 * 4 + 2], val.z);
        atomicAdd(&vs_l[j][e4 * 4 + 3], val.w);
    }
    us_l[irow][e4 * 4 + 0] = ua;
    us_l[irow][e4 * 4 + 1] = ub;
    us_l[irow][e4 * 4 + 2] = uc;
    us_l[irow][e4 * 4 + 3] = ud;
    __syncthreads();

    // ---- phase 2: circular conv, thread computes RxV/RxU at t=irow, e-slice e4 ----
    float rva = 0.f, rvb = 0.f, rvc = 0.f, rvd = 0.f;
    float rua = 0.f, rub = 0.f, ruc = 0.f, rud = 0.f;
    #pragma unroll 8
    for (int j = 0; j < SS; ++j) {
        int k = irow - j + SS;       // (t - j + 64), in [1,127]
        if (k >= NW) k -= NW;
        const float c = wtab[k];
        const float4 vv = *(const float4*)&vs_l[j][e4 * 4];
        const float4 uu = *(const float4*)&us_l[j][e4 * 4];
        rva += c * vv.x; rvb += c * vv.y; rvc += c * vv.z; rvd += c * vv.w;
        rua += c * uu.x; rub += c * uu.y; ruc += c * uu.z; rud += c * uu.w;
    }
    __syncthreads();                 // all reads done before overwrite
    {
        float4 rv; rv.x = rva; rv.y = rvb; rv.z = rvc; rv.w = rvd;
        float4 ru; ru.x = rua; ru.y = rub; ru.z = ruc; ru.w = rud;
        *(float4*)&vs_l[irow][e4 * 4] = rv;   // RxV[t][e]
        *(float4*)&us_l[irow][e4 * 4] = ru;   // RxU[t][e]
    }
    __syncthreads();

    // ---- phase 3: expand & write, dwordx4 stores ----
    float* obase = out + (((size_t)b * SEQ + (size_t)irow * SS) * HEADS + h) * EMB
                       + ebase + e4 * 4;
    const float4 ru = *(const float4*)&us_l[irow][e4 * 4];
    #pragma unroll 8
    for (int j = 0; j < SS; ++j) {
        float4 o = *(const float4*)&vs_l[j][e4 * 4];
        o.x += ru.x; o.y += ru.y; o.z += ru.z; o.w += ru.w;
        *(float4*)(obase + (size_t)j * HE) = o;
    }
}

// z_pb: zp[h][t] = s * sum_j o_[j] * w[h, (t-j+64)%127]
// out2[0, i*64+j, h] = zp[h][j] + zp[h][i].  Grid: 64 blocks (one per i).
__global__ __launch_bounds__(256) void zpb_kernel(const float* __restrict__ w,
                                                  const float* __restrict__ o_,
                                                  float* __restrict__ out2) {
    __shared__ float zp[HEADS][SS];
    __shared__ float osh[SS];
    __shared__ float wsh[HEADS * NW];

    const int tid = threadIdx.x;
    const int g   = blockIdx.x;   // i index

    if (tid < SS) osh[tid] = o_[tid];
    for (int idx = tid; idx < HEADS * NW; idx += 256) wsh[idx] = w[idx];
    __syncthreads();

    for (int idx = tid; idx < HEADS * SS; idx += 256) {
        const int h = idx / SS, t = idx % SS;
        float acc = 0.0f;
        #pragma unroll
        for (int j = 0; j < SS; ++j) {
            int k = t - j + 64;
            if (k >= NW) k -= NW;
            acc += osh[j] * wsh[h * NW + k];
        }
        zp[h][t] = acc * (float)SS;
    }
    __syncthreads();

    for (int idx = tid; idx < SS * HEADS; idx += 256) {
        const int tl = idx / HEADS, h = idx % HEADS;
        out2[(size_t)(g * SS + tl) * HEADS + h] = zp[h][tl] + zp[h][g];
    }
}

extern "C" void kernel_launch(void* const* d_in, const int* in_sizes, int n_in,
                              void* d_out, int out_size, void* d_ws, size_t ws_size,
                              hipStream_t stream) {
    const float* v  = (const float*)d_in[0];
    const float* w  = (const float*)d_in[1];
    const float* o_ = (const float*)d_in[2];
    float* out = (float*)d_out;

    pbv_kernel<<<BATCH * HEADS * 2, 512, 0, stream>>>(v, w, out);

    const size_t out1_elems = (size_t)BATCH * SEQ * HEADS * EMB;
    zpb_kernel<<<SS, 256, 0, stream>>>(w, o_, out + out1_elems);
}